// Round 8
// baseline (81.701 us; speedup 1.0000x reference)
//
#include <hip/hip_runtime.h>

#define T_LEN   1048576
#define CHUNK   16                           // 16 outputs/thread -> 1 wave/SIMD, minimal warm redundancy
#define WARM    192                          // rho^192 ~ 0.16; truncation ~1e-6 (floor 1.9e-6, thr 7.5e-6)
#define SBLOCK  256
#define OUTS_PER_BLOCK (SBLOCK * CHUNK)      // 4096
#define SGRID   (T_LEN / OUTS_PER_BLOCK)     // 256 blocks -> 1 block/CU
#define WIN     (WARM + OUTS_PER_BLOCK)      // 4288 floats per block window
#define WIN4    (WIN / 4)                    // 1072 float4
#define LDS_DW  (WIN + (WIN / 64) * 4)       // +4 dwords pad per 64 -> 4556 dwords (18.2 KB)
#define RGRID   256

typedef float v2f __attribute__((ext_vector_type(2)));

// ---------------- Kernel A: per-block fp64 partial sums (no atomics) --------------
__global__ __launch_bounds__(256)
void var_partials_kernel(const float* __restrict__ y, double2* __restrict__ ws) {
    int tid = blockIdx.x * blockDim.x + threadIdx.x;
    const float4* y4 = (const float4*)y;
    const int stride = RGRID * 256;          // 65536
    float4 v0 = y4[tid];
    float4 v1 = y4[tid + stride];
    float4 v2 = y4[tid + 2 * stride];
    float4 v3 = y4[tid + 3 * stride];
    double s = 0.0, s2 = 0.0;
    #define ACC(v) { double a=(v).x,b=(v).y,c=(v).z,d=(v).w; s += (a+b)+(c+d); s2 += (a*a+b*b)+(c*c+d*d); }
    ACC(v0) ACC(v1) ACC(v2) ACC(v3)
    #undef ACC
    for (int off = 32; off >= 1; off >>= 1) {
        s  += __shfl_down(s,  off, 64);
        s2 += __shfl_down(s2, off, 64);
    }
    __shared__ double lsum[4], lsq[4];
    int lane = threadIdx.x & 63, wv = threadIdx.x >> 6;
    if (lane == 0) { lsum[wv] = s; lsq[wv] = s2; }
    __syncthreads();
    if (threadIdx.x == 0) {
        double2 o;
        o.x = (lsum[0] + lsum[1]) + (lsum[2] + lsum[3]);
        o.y = (lsq[0]  + lsq[1])  + (lsq[2]  + lsq[3]);
        ws[blockIdx.x] = o;
    }
}

// ---------------- Recurrence step: y-precomputed + bit-magic rcp, 3-deep chain -----
// h' = ky_h + E*q + PH_h*h + (A*y^2)*(1/h);  q' analogous (packed lane 1).
// 1/h: exponent-flip seed r0 (<=5% err) + 1 Newton, reassociated as (yv*r0)*(2-h*r0)
// so the Newton multiply runs PARALLEL to the residual:
//   chain: h -> r0 (int sub) -> {e = fma(-h,r0,2)  ||  g = yv*r0} -> h' = fma(g,e,m2)
// Depth 3 fast-VALU ops; no trans pipe. Systematic rcp err ~0.0016% -> ~1e-9 on h'.
struct ChnC { v2f G, DC, ER, PH, AV; };
struct Pre  { v2f ky, yv; };

__device__ __forceinline__ Pre mk_pre(float yv_, const ChnC& C) {
    Pre p;
    float y2 = yv_ * yv_;
    p.ky = __builtin_elementwise_fma(C.G, (v2f){yv_, yv_}, C.DC);
    p.yv = C.AV * (v2f){y2, y2};
    return p;
}

__device__ __forceinline__ void chn_step(const Pre& p, float& h, float& q, const ChnC& C) {
    float r0 = __uint_as_float(0x7EF311C3u - __float_as_uint(h));  // ~5% approx of 1/h
    float e  = fmaf(-h, r0, 2.0f);                 // Newton residual   (chain lvl 2)
    v2f  g   = p.yv * (v2f){r0, r0};               // parallel with e   (chain lvl 2)
    v2f m = __builtin_elementwise_fma(C.ER, (v2f){q, q}, p.ky);   // off-chain
    m     = __builtin_elementwise_fma(C.PH, (v2f){h, h}, m);      // parallel (lvl 1)
    m     = __builtin_elementwise_fma(g, (v2f){e, e}, m);         // lvl 3: yv*r0*e
    h = m.x;
    q = m.y;
}

// padded LDS index: +4 dwords per 64 (keeps 16B alignment of 4-aligned d)
__device__ __forceinline__ float4 lds_r4(const float* b, int d) {
    return *(const float4*)&b[d + ((d >> 6) << 2)];
}
__device__ __forceinline__ void lds_w4(float* b, int d, float4 v) {
    *(float4*)&b[d + ((d >> 6) << 2)] = v;
}

// ---------------- Kernel B: LDS-staged chunked scan --------------------------------
__global__ __launch_bounds__(SBLOCK)
void chn_scan_kernel(const float* __restrict__ y, float* __restrict__ out,
                     const double2* __restrict__ ws,
                     const float* __restrict__ p_omega, const float* __restrict__ p_alpha,
                     const float* __restrict__ p_phi,   const float* __restrict__ p_lam,
                     const float* __restrict__ p_gam1,  const float* __restrict__ p_gam2,
                     const float* __restrict__ p_vphi,  const float* __restrict__ p_rho) {
    __shared__ __align__(16) float ybuf[LDS_DW];

    const int B0    = blockIdx.x * OUTS_PER_BLOCK;
    const int gbase = (blockIdx.x == 0) ? 0 : (B0 - WARM);

    // ---- stage window into LDS, coalesced global float4 reads ----
    {
        const float4* g4 = (const float4*)(y + gbase);
        for (int i = threadIdx.x; i < WIN4; i += SBLOCK) {
            lds_w4(ybuf, 4 * i, g4[i]);
        }
    }

    // ---- constants (overlaps with staging loads) ----
    const float omega = *p_omega, alpha = *p_alpha, phi = *p_phi, lam = *p_lam;
    const float gam1 = *p_gam1, gam2 = *p_gam2, vphi = *p_vphi, rho = *p_rho;
    const float onemphi = 1.0f - phi;
    const float c0  = omega * (1.0f - rho);
    const float cv2 = -2.0f * gam2 * vphi;
    const float c1  = -2.0f * gam1 * alpha;
    const float A   = fmaf(onemphi, vphi, alpha);
    const float B   = fmaf(onemphi, cv2, c1);
    const float E   = onemphi * rho;
    ChnC C;
    C.G  = (v2f){B - 2.0f * A * lam,            cv2 - 2.0f * vphi * lam};
    C.DC = (v2f){onemphi * c0 - A,              c0 - vphi};
    C.ER = (v2f){E,                             rho};
    C.PH = (v2f){phi - B * lam + A * lam * lam, vphi * lam * lam - cv2 * lam};
    C.AV = (v2f){A,                             vphi};

    // ---- variance: wave-redundant reduce of 256 double2 partials ----
    int lane = threadIdx.x & 63;
    double s = 0.0, s2 = 0.0;
    #pragma unroll
    for (int k = 0; k < 4; ++k) {
        double2 v = ws[lane + 64 * k];
        s += v.x; s2 += v.y;
    }
    #pragma unroll
    for (int off = 32; off >= 1; off >>= 1) {
        s  += __shfl_xor(s,  off, 64);
        s2 += __shfl_xor(s2, off, 64);
    }
    const double inv_t = 1.0 / (double)T_LEN;
    double mean = s * inv_t;
    const float var = (float)(s2 * inv_t - mean * mean);

    __syncthreads();

    const int t0 = B0 + threadIdx.x * CHUNK;
    float h = var, q = var;
    float4* out4 = (float4*)(out + t0);

    if (blockIdx.x != 0) {
        // ---- uniform fast path: WARM steps, precompute-next-8 overlap ----
        const int dw = threadIdx.x * CHUNK;
        float4 a = lds_r4(ybuf, dw + 0);
        float4 b = lds_r4(ybuf, dw + 4);
        Pre pc[8];
        pc[0] = mk_pre(a.x, C); pc[1] = mk_pre(a.y, C);
        pc[2] = mk_pre(a.z, C); pc[3] = mk_pre(a.w, C);
        pc[4] = mk_pre(b.x, C); pc[5] = mk_pre(b.y, C);
        pc[6] = mk_pre(b.z, C); pc[7] = mk_pre(b.w, C);
        for (int f = 0; f < WARM / 4; f += 2) {
            // last iter loads dwords WARM..WARM+7 = y[t0..t0+7] (the emit inputs)
            float4 na = lds_r4(ybuf, dw + 4 * (f + 2));
            float4 nb = lds_r4(ybuf, dw + 4 * (f + 3));
            #pragma unroll
            for (int j = 0; j < 8; ++j) chn_step(pc[j], h, q, C);
            pc[0] = mk_pre(na.x, C); pc[1] = mk_pre(na.y, C);
            pc[2] = mk_pre(na.z, C); pc[3] = mk_pre(na.w, C);
            pc[4] = mk_pre(nb.x, C); pc[5] = mk_pre(nb.y, C);
            pc[6] = mk_pre(nb.z, C); pc[7] = mk_pre(nb.w, C);
        }
        // pc[] holds y[t0..t0+7]; fetch y[t0+8..t0+15]
        float4 c = lds_r4(ybuf, dw + WARM + 8);
        float4 d = lds_r4(ybuf, dw + WARM + 12);
        float4 o;
        o.x = h; chn_step(pc[0], h, q, C);
        o.y = h; chn_step(pc[1], h, q, C);
        o.z = h; chn_step(pc[2], h, q, C);
        o.w = h; chn_step(pc[3], h, q, C);
        out4[0] = o;
        o.x = h; chn_step(pc[4], h, q, C);
        o.y = h; chn_step(pc[5], h, q, C);
        o.z = h; chn_step(pc[6], h, q, C);
        o.w = h; chn_step(pc[7], h, q, C);
        out4[1] = o;
        o.x = h; chn_step(mk_pre(c.x, C), h, q, C);
        o.y = h; chn_step(mk_pre(c.y, C), h, q, C);
        o.z = h; chn_step(mk_pre(c.z, C), h, q, C);
        o.w = h; chn_step(mk_pre(c.w, C), h, q, C);
        out4[2] = o;
        o.x = h; chn_step(mk_pre(d.x, C), h, q, C);
        o.y = h; chn_step(mk_pre(d.y, C), h, q, C);
        o.z = h; chn_step(mk_pre(d.z, C), h, q, C);
        o.w = h; chn_step(mk_pre(d.w, C), h, q, C);
        out4[3] = o;
    } else {
        // ---- block 0: exact ramp from t=0 (gbase==0, LDS dword == global idx) ----
        const int nW = (t0 < WARM) ? t0 : WARM;  // t0 is a multiple of 16; WARM=192=12*16
        const int d0 = t0 - nW;
        for (int f = 0; f < nW / 4; ++f) {
            float4 v = lds_r4(ybuf, d0 + 4 * f);
            chn_step(mk_pre(v.x, C), h, q, C);
            chn_step(mk_pre(v.y, C), h, q, C);
            chn_step(mk_pre(v.z, C), h, q, C);
            chn_step(mk_pre(v.w, C), h, q, C);
        }
        #pragma unroll
        for (int j = 0; j < CHUNK / 4; ++j) {
            float4 v = lds_r4(ybuf, t0 + 4 * j);
            float4 o;
            o.x = h; chn_step(mk_pre(v.x, C), h, q, C);
            o.y = h; chn_step(mk_pre(v.y, C), h, q, C);
            o.z = h; chn_step(mk_pre(v.z, C), h, q, C);
            o.w = h; chn_step(mk_pre(v.w, C), h, q, C);
            out4[j] = o;
        }
    }
}

extern "C" void kernel_launch(void* const* d_in, const int* in_sizes, int n_in,
                              void* d_out, int out_size, void* d_ws, size_t ws_size,
                              hipStream_t stream) {
    const float* y = (const float*)d_in[0];
    float* out = (float*)d_out;
    double2* ws = (double2*)d_ws;   // 256 double2 partials = 4 KB

    var_partials_kernel<<<RGRID, 256, 0, stream>>>(y, ws);

    chn_scan_kernel<<<SGRID, SBLOCK, 0, stream>>>(
        y, out, ws,
        (const float*)d_in[1], (const float*)d_in[2], (const float*)d_in[3],
        (const float*)d_in[4], (const float*)d_in[5], (const float*)d_in[6],
        (const float*)d_in[7], (const float*)d_in[8]);
}